// Round 1
// baseline (41.103 us; speedup 1.0000x reference)
//
#include <hip/hip_runtime.h>

// Problem constants (fixed by the reference): B=32, N=128, L=16, F=32, NAVG=50
#define BB 32
#define NN 128
#define LL 16
#define FF 32
constexpr float INV_NAVG = 1.0f / 50.0f;

// ---------------------------------------------------------------------------
// Kernel 1: rowsum[b,i,l] = (1/NAVG) * sum_j inputs[b,i,j,l]
// grid = B*N blocks, 256 threads. Lane pattern: l = t&15, group g = t>>4.
// Wave reads 256B contiguous per iteration (coalesced).
// ---------------------------------------------------------------------------
__global__ __launch_bounds__(256) void k_rowsum(const float* __restrict__ in,
                                                float* __restrict__ rs) {
    int blk = blockIdx.x;          // b*N + i
    int t = threadIdx.x;
    int l = t & 15, g = t >> 4;    // 16 groups of 16 lanes
    const float* base = in + (size_t)blk * (NN * LL);
    float s = 0.f;
#pragma unroll
    for (int k = 0; k < 8; ++k) {
        int j = g + 16 * k;
        s += base[j * LL + l];
    }
    __shared__ float red[256];
    red[t] = s;
    __syncthreads();
#pragma unroll
    for (int st = 8; st >= 1; st >>= 1) {
        if (g < st) red[t] += red[t + st * 16];
        __syncthreads();
    }
    if (t < LL) rs[(size_t)blk * LL + t] = red[t] * INV_NAVG;
}

// ---------------------------------------------------------------------------
// Kernel 2: per-batch precompute. 1 block per b (32 blocks, 256 threads).
//   totsum[l]  = (1/NAVG) * sum_i rowsum[b,i,l]
//   a2[b,i,f]  = sum_l rowsum*w2 + sum_l totsum*w1 + bias[f]
//   rw3[b,i,f] = sum_l rowsum*w3
//   rwD[b,i,f] = sum_l rowsum*w4 + sum_l totsum*w5 + diag_bias[f]
// ---------------------------------------------------------------------------
__global__ __launch_bounds__(256) void k_precomp(const float* __restrict__ rs,
                                                 const float* __restrict__ w,
                                                 const float* __restrict__ bias,
                                                 const float* __restrict__ dbias,
                                                 float* __restrict__ a2,
                                                 float* __restrict__ rw3,
                                                 float* __restrict__ rwD) {
    int b = blockIdx.x;
    int t = threadIdx.x;
    __shared__ float srs[NN * LL];   // 8KB: rowsum[b,:,:]
    __shared__ float red[256];
    __shared__ float tot[LL];
    __shared__ float tbase[FF];
    __shared__ float ttd[FF];
    const float* rsb = rs + (size_t)b * NN * LL;
#pragma unroll
    for (int r = 0; r < 8; ++r) srs[t + 256 * r] = rsb[t + 256 * r];
    __syncthreads();

    // totsum
    int l = t & 15, g = t >> 4;
    float s = 0.f;
#pragma unroll
    for (int k = 0; k < 8; ++k) s += srs[(g + 16 * k) * LL + l];
    red[t] = s;
    __syncthreads();
#pragma unroll
    for (int st = 8; st >= 1; st >>= 1) {
        if (g < st) red[t] += red[t + st * 16];
        __syncthreads();
    }
    if (t < LL) tot[t] = red[t] * INV_NAVG;
    __syncthreads();

    // per-b f-vectors: base (op1 + bias), totdiag (op5 + diag_bias)
    if (t < FF) {
        int f = t;
        float bs = bias[f], td = dbias[f];
#pragma unroll
        for (int q = 0; q < LL; ++q) {
            float tv = tot[q];
            bs += tv * w[(q * 6 + 1) * FF + f];
            td += tv * w[(q * 6 + 5) * FF + f];
        }
        tbase[f] = bs;
        ttd[f] = td;
    }
    __syncthreads();

    // per-(i,f) arrays
    int f = t & 31, ig = t >> 5;     // 8 groups
    float w2r[LL], w3r[LL], w4r[LL];
#pragma unroll
    for (int q = 0; q < LL; ++q) {
        w2r[q] = w[(q * 6 + 2) * FF + f];
        w3r[q] = w[(q * 6 + 3) * FF + f];
        w4r[q] = w[(q * 6 + 4) * FF + f];
    }
    float tb = tbase[f], tdv = ttd[f];
    for (int k = 0; k < 16; ++k) {
        int i = ig + 8 * k;
        float s2 = 0.f, s3 = 0.f, s4 = 0.f;
#pragma unroll
        for (int q = 0; q < LL; ++q) {
            float rv = srs[i * LL + q];   // broadcast across the 32-lane group
            s2 += rv * w2r[q];
            s3 += rv * w3r[q];
            s4 += rv * w4r[q];
        }
        size_t o = ((size_t)b * NN + i) * FF + f;
        a2[o]  = s2 + tb;
        rw3[o] = s3;
        rwD[o] = s4 + tdv;
    }
}

// ---------------------------------------------------------------------------
// Kernel 3: main. 1 block per (b,i) row. 256 threads: f = t&31, jg = t>>5.
// out[b,i,j,f] = relu( in[b,i,j,:].w0[:,f] + a2[b,i,f] + rw3[b,j,f]
//                      + (i==j)*rwD[b,i,f] )
// ---------------------------------------------------------------------------
__global__ __launch_bounds__(256) void k_main(const float* __restrict__ in,
                                              const float* __restrict__ w,
                                              const float* __restrict__ a2,
                                              const float* __restrict__ rw3,
                                              const float* __restrict__ rwD,
                                              float* __restrict__ out) {
    int blk = blockIdx.x;          // b*N + i
    int b = blk >> 7;
    int i = blk & 127;
    int t = threadIdx.x;
    int f = t & 31, jg = t >> 5;   // 8 j-groups

    __shared__ float inRow[NN * LL];   // 8KB: inputs[b,i,:,:]
    const float4* src4 = reinterpret_cast<const float4*>(in + (size_t)blk * (NN * LL));
    float4* dst4 = reinterpret_cast<float4*>(inRow);
    dst4[t] = src4[t];
    dst4[t + 256] = src4[t + 256];
    __syncthreads();

    float w0r[LL];
#pragma unroll
    for (int l = 0; l < LL; ++l) w0r[l] = w[l * 6 * FF + f];   // w[l,0,f]

    float a2v = a2[(size_t)blk * FF + f];
    float rwDv = rwD[(size_t)blk * FF + f];
    const float* rw3b = rw3 + (size_t)b * NN * FF + f;
    float* outb = out + (size_t)blk * NN * FF + f;

#pragma unroll 4
    for (int k = 0; k < 16; ++k) {
        int j = jg + 8 * k;
        float acc = a2v + rw3b[(size_t)j * FF] + ((j == i) ? rwDv : 0.f);
        const float4* xr = reinterpret_cast<const float4*>(&inRow[j * LL]);
        float4 x0 = xr[0], x1 = xr[1], x2 = xr[2], x3 = xr[3];
        acc += x0.x * w0r[0] + x0.y * w0r[1] + x0.z * w0r[2] + x0.w * w0r[3];
        acc += x1.x * w0r[4] + x1.y * w0r[5] + x1.z * w0r[6] + x1.w * w0r[7];
        acc += x2.x * w0r[8] + x2.y * w0r[9] + x2.z * w0r[10] + x2.w * w0r[11];
        acc += x3.x * w0r[12] + x3.y * w0r[13] + x3.z * w0r[14] + x3.w * w0r[15];
        outb[(size_t)j * FF] = fmaxf(acc, 0.f);
    }
}

extern "C" void kernel_launch(void* const* d_in, const int* in_sizes, int n_in,
                              void* d_out, int out_size, void* d_ws, size_t ws_size,
                              hipStream_t stream) {
    const float* in    = (const float*)d_in[0];   // [B,N,N,L] fp32
    const float* w     = (const float*)d_in[1];   // [L,6,F]
    const float* bias  = (const float*)d_in[2];   // [F]
    const float* dbias = (const float*)d_in[3];   // [F]
    float* out = (float*)d_out;                   // [B,N,N,F] fp32
    float* ws  = (float*)d_ws;

    float* rs  = ws;                       // B*N*L   = 65536 floats
    float* a2  = rs  + (size_t)BB * NN * LL;   // B*N*F = 131072
    float* rw3 = a2  + (size_t)BB * NN * FF;   // 131072
    float* rwD = rw3 + (size_t)BB * NN * FF;   // 131072  (total ~1.84 MB)

    k_rowsum <<<BB * NN, 256, 0, stream>>>(in, rs);
    k_precomp<<<BB,      256, 0, stream>>>(rs, w, bias, dbias, a2, rw3, rwD);
    k_main   <<<BB * NN, 256, 0, stream>>>(in, w, a2, rw3, rwD, out);
}